// Round 1
// baseline (426.677 us; speedup 1.0000x reference)
//
#include <hip/hip_runtime.h>

#define HH 512
#define WW 512
#define NPLANES 48              // B*C = 16*3
#define TILE 32
#define HALO 11
#define ITILE 54                // TILE + 2*HALO
#define KSIZE 23
#define C1V 1.0e-4f             // 0.01^2
#define C2V 9.0e-4f             // 0.03^2

__global__ void ssim_init_kernel(float* acc) {
    acc[0] = 0.0f;
}

__global__ __launch_bounds__(256) void ssim_main_kernel(
    const float* __restrict__ in, const float* __restrict__ tg,
    const float* __restrict__ w, float* __restrict__ acc)
{
    __shared__ float sIn[ITILE][ITILE];
    __shared__ float sTg[ITILE][ITILE];
    __shared__ float hbuf[5][ITILE][TILE];
    __shared__ float sg[KSIZE];
    __shared__ float swsum[4];

    const int tid = threadIdx.x;

    // 1D gaussian taps = row sums of the (separable, normalized) 2D kernel.
    if (tid < KSIZE) {
        float s = 0.f;
        #pragma unroll
        for (int j = 0; j < KSIZE; ++j) s += w[tid * KSIZE + j];
        sg[tid] = s;
    }

    const int plane = blockIdx.z;
    const int x0 = blockIdx.x * TILE - HALO;
    const int y0 = blockIdx.y * TILE - HALO;
    const float* __restrict__ inp = in + (size_t)plane * (HH * WW);
    const float* __restrict__ tgp = tg + (size_t)plane * (HH * WW);

    // ---- stage input tiles (zero-padded at image borders) ----
    for (int t = tid; t < ITILE * ITILE; t += 256) {
        int r = t / ITILE, c = t - r * ITILE;
        int gy = y0 + r, gx = x0 + c;
        bool ok = (gy >= 0) & (gy < HH) & (gx >= 0) & (gx < WW);
        int idx = gy * WW + gx;
        sIn[r][c] = ok ? inp[idx] : 0.f;
        sTg[r][c] = ok ? tgp[idx] : 0.f;
    }
    __syncthreads();

    // ---- horizontal pass: 5 channels, all 54 rows x 32 cols ----
    for (int t = tid; t < ITILE * TILE; t += 256) {
        int r = t >> 5, c = t & 31;
        float hx = 0.f, ht = 0.f, hxx = 0.f, htt = 0.f, hxt = 0.f;
        #pragma unroll
        for (int j = 0; j < KSIZE; ++j) {
            float g = sg[j];
            float a = sIn[r][c + j];
            float b = sTg[r][c + j];
            float ga = g * a, gb = g * b;
            hx  += ga;
            ht  += gb;
            hxx += ga * a;
            htt += gb * b;
            hxt += ga * b;
        }
        hbuf[0][r][c] = hx;
        hbuf[1][r][c] = ht;
        hbuf[2][r][c] = hxx;
        hbuf[3][r][c] = htt;
        hbuf[4][r][c] = hxt;
    }
    __syncthreads();

    // ---- vertical pass + SSIM map + local sum ----
    float lsum = 0.f;
    for (int t = tid; t < TILE * TILE; t += 256) {
        int r = t >> 5, c = t & 31;
        float vx = 0.f, vt = 0.f, vxx = 0.f, vtt = 0.f, vxt = 0.f;
        #pragma unroll
        for (int j = 0; j < KSIZE; ++j) {
            float g = sg[j];
            vx  += g * hbuf[0][r + j][c];
            vt  += g * hbuf[1][r + j][c];
            vxx += g * hbuf[2][r + j][c];
            vtt += g * hbuf[3][r + j][c];
            vxt += g * hbuf[4][r + j][c];
        }
        float m1s = vx * vx, m2s = vt * vt, m12 = vx * vt;
        float s1 = vxx - m1s, s2 = vtt - m2s, s12 = vxt - m12;
        float num = (2.f * m12 + C1V) * (2.f * s12 + C2V);
        float den = (m1s + m2s + C1V) * (s1 + s2 + C2V);
        lsum += num / den;
    }

    // ---- block reduction: wave shuffle, then across 4 waves ----
    #pragma unroll
    for (int off = 32; off > 0; off >>= 1)
        lsum += __shfl_down(lsum, off, 64);
    if ((tid & 63) == 0) swsum[tid >> 6] = lsum;
    __syncthreads();
    if (tid == 0) {
        float s = swsum[0] + swsum[1] + swsum[2] + swsum[3];
        atomicAdd(acc, s);
    }
}

__global__ void ssim_final_kernel(const float* __restrict__ acc, float* __restrict__ out) {
    out[0] = 1.0f - acc[0] * (1.0f / ((float)NPLANES * HH * WW));
}

extern "C" void kernel_launch(void* const* d_in, const int* in_sizes, int n_in,
                              void* d_out, int out_size, void* d_ws, size_t ws_size,
                              hipStream_t stream) {
    const float* inp = (const float*)d_in[0];
    const float* tgt = (const float*)d_in[1];
    const float* wgt = (const float*)d_in[2];
    float* out = (float*)d_out;
    float* acc = (float*)d_ws;

    ssim_init_kernel<<<1, 1, 0, stream>>>(acc);
    dim3 grid(WW / TILE, HH / TILE, NPLANES);
    ssim_main_kernel<<<grid, 256, 0, stream>>>(inp, tgt, wgt, acc);
    ssim_final_kernel<<<1, 1, 0, stream>>>(acc, out);
}

// Round 2
// 377.207 us; speedup vs baseline: 1.1311x; 1.1311x over previous
//
#include <hip/hip_runtime.h>

#define HH 512
#define WW 512
#define NPLANES 48              // B*C = 16*3
#define TILE 32
#define HALO 11
#define ITILE 54                // TILE + 2*HALO (rows / used cols)
#define IT_W 56                 // padded row length (floats) -> 224 B, 16B-aligned rows
#define KSIZE 23
#define C1V 1.0e-4f             // 0.01^2
#define C2V 9.0e-4f             // 0.03^2

__global__ void ssim_init_kernel(float* acc) {
    acc[0] = 0.0f;
}

__global__ __launch_bounds__(256) void ssim_main_kernel(
    const float* __restrict__ in, const float* __restrict__ tg,
    const float* __restrict__ w, float* __restrict__ acc)
{
    __shared__ float sIn[ITILE][IT_W];
    __shared__ float sTg[ITILE][IT_W];
    __shared__ float hbuf[5][ITILE][TILE];
    __shared__ float sg[KSIZE];
    __shared__ float swsum[4];

    const int tid = threadIdx.x;

    // 1D gaussian taps = row sums of the (separable, normalized) 2D kernel.
    if (tid < KSIZE) {
        float s = 0.f;
        #pragma unroll
        for (int j = 0; j < KSIZE; ++j) s += w[tid * KSIZE + j];
        sg[tid] = s;
    }

    const int plane = blockIdx.z;
    const int x0 = blockIdx.x * TILE - HALO;
    const int y0 = blockIdx.y * TILE - HALO;
    const float* __restrict__ inp = in + (size_t)plane * (HH * WW);
    const float* __restrict__ tgp = tg + (size_t)plane * (HH * WW);

    // ---- stage input tiles (zero-padded at image borders) ----
    for (int t = tid; t < ITILE * ITILE; t += 256) {
        int r = t / ITILE, c = t - r * ITILE;
        int gy = y0 + r, gx = x0 + c;
        bool ok = (gy >= 0) & (gy < HH) & (gx >= 0) & (gx < WW);
        int idx = gy * WW + gx;
        sIn[r][c] = ok ? inp[idx] : 0.f;
        sTg[r][c] = ok ? tgp[idx] : 0.f;
    }
    __syncthreads();

    // ---- horizontal pass: each task = 1 row x 4 consecutive cols ----
    // tasks: 54 rows x 8 col-groups = 432
    for (int t = tid; t < ITILE * (TILE / 4); t += 256) {
        int r = t >> 3;
        int cg = (t & 7) << 2;            // starting col: 0,4,...,28

        float wa[28], wb[28];
        const float4* pa = (const float4*)&sIn[r][cg];
        const float4* pb = (const float4*)&sTg[r][cg];
        #pragma unroll
        for (int q = 0; q < 7; ++q) {
            float4 va = pa[q];
            float4 vb = pb[q];
            wa[4*q+0] = va.x; wa[4*q+1] = va.y; wa[4*q+2] = va.z; wa[4*q+3] = va.w;
            wb[4*q+0] = vb.x; wb[4*q+1] = vb.y; wb[4*q+2] = vb.z; wb[4*q+3] = vb.w;
        }

        float hx[4]  = {0.f,0.f,0.f,0.f};
        float ht[4]  = {0.f,0.f,0.f,0.f};
        float hxx[4] = {0.f,0.f,0.f,0.f};
        float htt[4] = {0.f,0.f,0.f,0.f};
        float hxt[4] = {0.f,0.f,0.f,0.f};
        #pragma unroll
        for (int j = 0; j < KSIZE; ++j) {
            float g = sg[j];
            #pragma unroll
            for (int c4 = 0; c4 < 4; ++c4) {
                float a = wa[j + c4], b = wb[j + c4];
                float ga = g * a, gb = g * b;
                hx[c4]  += ga;
                ht[c4]  += gb;
                hxx[c4] += ga * a;
                htt[c4] += gb * b;
                hxt[c4] += ga * b;
            }
        }
        *(float4*)&hbuf[0][r][cg] = make_float4(hx[0],  hx[1],  hx[2],  hx[3]);
        *(float4*)&hbuf[1][r][cg] = make_float4(ht[0],  ht[1],  ht[2],  ht[3]);
        *(float4*)&hbuf[2][r][cg] = make_float4(hxx[0], hxx[1], hxx[2], hxx[3]);
        *(float4*)&hbuf[3][r][cg] = make_float4(htt[0], htt[1], htt[2], htt[3]);
        *(float4*)&hbuf[4][r][cg] = make_float4(hxt[0], hxt[1], hxt[2], hxt[3]);
    }
    __syncthreads();

    // ---- vertical pass: each thread = 4 consecutive rows x 1 col ----
    const int r0 = (tid >> 5) << 2;       // 0,4,...,28
    const int c  = tid & 31;

    float res[5][4];
    #pragma unroll
    for (int ch = 0; ch < 5; ++ch) {
        float win[26];
        #pragma unroll
        for (int q = 0; q < 26; ++q) win[q] = hbuf[ch][r0 + q][c];
        float a0 = 0.f, a1 = 0.f, a2 = 0.f, a3 = 0.f;
        #pragma unroll
        for (int j = 0; j < KSIZE; ++j) {
            float g = sg[j];
            a0 += g * win[j + 0];
            a1 += g * win[j + 1];
            a2 += g * win[j + 2];
            a3 += g * win[j + 3];
        }
        res[ch][0] = a0; res[ch][1] = a1; res[ch][2] = a2; res[ch][3] = a3;
    }

    float lsum = 0.f;
    #pragma unroll
    for (int rr = 0; rr < 4; ++rr) {
        float vx = res[0][rr], vt = res[1][rr];
        float vxx = res[2][rr], vtt = res[3][rr], vxt = res[4][rr];
        float m1s = vx * vx, m2s = vt * vt, m12 = vx * vt;
        float s1 = vxx - m1s, s2 = vtt - m2s, s12 = vxt - m12;
        float num = (2.f * m12 + C1V) * (2.f * s12 + C2V);
        float den = (m1s + m2s + C1V) * (s1 + s2 + C2V);
        lsum += num / den;
    }

    // ---- block reduction: wave shuffle, then across 4 waves ----
    #pragma unroll
    for (int off = 32; off > 0; off >>= 1)
        lsum += __shfl_down(lsum, off, 64);
    if ((tid & 63) == 0) swsum[tid >> 6] = lsum;
    __syncthreads();
    if (tid == 0) {
        float s = swsum[0] + swsum[1] + swsum[2] + swsum[3];
        atomicAdd(acc, s);
    }
}

__global__ void ssim_final_kernel(const float* __restrict__ acc, float* __restrict__ out) {
    out[0] = 1.0f - acc[0] * (1.0f / ((float)NPLANES * HH * WW));
}

extern "C" void kernel_launch(void* const* d_in, const int* in_sizes, int n_in,
                              void* d_out, int out_size, void* d_ws, size_t ws_size,
                              hipStream_t stream) {
    const float* inp = (const float*)d_in[0];
    const float* tgt = (const float*)d_in[1];
    const float* wgt = (const float*)d_in[2];
    float* out = (float*)d_out;
    float* acc = (float*)d_ws;

    ssim_init_kernel<<<1, 1, 0, stream>>>(acc);
    dim3 grid(WW / TILE, HH / TILE, NPLANES);
    ssim_main_kernel<<<grid, 256, 0, stream>>>(inp, tgt, wgt, acc);
    ssim_final_kernel<<<1, 1, 0, stream>>>(acc, out);
}

// Round 3
// 377.126 us; speedup vs baseline: 1.1314x; 1.0002x over previous
//
#include <hip/hip_runtime.h>

#define HH 512
#define WW 512
#define NPLANES 48              // B*C = 16*3
#define TILE 32
#define HALO 11
#define ITILE 54                // TILE + 2*HALO
#define IT_W 56                 // padded row length for sIn/sTg (16B-aligned rows)
#define HB_W 60                 // padded row length for transposed hbuf (16B-aligned, bank-spread)
#define KSIZE 23
#define NBLK (16 * 16 * NPLANES)
#define C1V 1.0e-4f             // 0.01^2
#define C2V 9.0e-4f             // 0.03^2

__global__ __launch_bounds__(256) void ssim_main_kernel(
    const float* __restrict__ in, const float* __restrict__ tg,
    const float* __restrict__ w, float* __restrict__ partial)
{
    __shared__ __align__(16) float sIn[ITILE][IT_W];
    __shared__ __align__(16) float sTg[ITILE][IT_W];
    __shared__ __align__(16) float hbT[5][TILE][HB_W];  // [ch][col][row]
    __shared__ float sg[KSIZE];
    __shared__ float swsum[4];

    const int tid = threadIdx.x;

    // 1D gaussian taps = row sums of the (separable, normalized) 2D kernel.
    if (tid < KSIZE) {
        float s = 0.f;
        #pragma unroll
        for (int j = 0; j < KSIZE; ++j) s += w[tid * KSIZE + j];
        sg[tid] = s;
    }

    const int blk = blockIdx.x;
    const int plane = blk / 256;
    const int t2 = blk - plane * 256;        // 16x16 tiles
    const int x0 = (t2 & 15) * TILE - HALO;
    const int y0 = (t2 >> 4) * TILE - HALO;
    const float* __restrict__ inp = in + (size_t)plane * (HH * WW);
    const float* __restrict__ tgp = tg + (size_t)plane * (HH * WW);

    // ---- stage input tiles (zero-padded at image borders) ----
    for (int t = tid; t < ITILE * ITILE; t += 256) {
        int r = t / ITILE, c = t - r * ITILE;
        int gy = y0 + r, gx = x0 + c;
        bool ok = (gy >= 0) & (gy < HH) & (gx >= 0) & (gx < WW);
        int idx = gy * WW + gx;
        sIn[r][c] = ok ? inp[idx] : 0.f;
        sTg[r][c] = ok ? tgp[idx] : 0.f;
    }
    __syncthreads();

    // ---- horizontal pass: task = 1 row x 4 cols; write transposed ----
    for (int t = tid; t < ITILE * (TILE / 4); t += 256) {
        int r = t >> 3;
        int cg = (t & 7) << 2;

        float wa[28], wb[28], wa2[28], wb2[28], wab[28];
        const float4* pa = (const float4*)&sIn[r][cg];
        const float4* pb = (const float4*)&sTg[r][cg];
        #pragma unroll
        for (int q = 0; q < 7; ++q) {
            float4 va = pa[q];
            float4 vb = pb[q];
            wa[4*q+0] = va.x; wa[4*q+1] = va.y; wa[4*q+2] = va.z; wa[4*q+3] = va.w;
            wb[4*q+0] = vb.x; wb[4*q+1] = vb.y; wb[4*q+2] = vb.z; wb[4*q+3] = vb.w;
        }
        #pragma unroll
        for (int q = 0; q < 28; ++q) {
            wa2[q] = wa[q] * wa[q];
            wb2[q] = wb[q] * wb[q];
            wab[q] = wa[q] * wb[q];
        }

        float hx[4]  = {0.f,0.f,0.f,0.f};
        float ht[4]  = {0.f,0.f,0.f,0.f};
        float hxx[4] = {0.f,0.f,0.f,0.f};
        float htt[4] = {0.f,0.f,0.f,0.f};
        float hxt[4] = {0.f,0.f,0.f,0.f};
        #pragma unroll
        for (int j = 0; j < KSIZE; ++j) {
            float g = sg[j];
            #pragma unroll
            for (int c4 = 0; c4 < 4; ++c4) {
                hx[c4]  += g * wa[j + c4];
                ht[c4]  += g * wb[j + c4];
                hxx[c4] += g * wa2[j + c4];
                htt[c4] += g * wb2[j + c4];
                hxt[c4] += g * wab[j + c4];
            }
        }
        #pragma unroll
        for (int i = 0; i < 4; ++i) {
            hbT[0][cg + i][r] = hx[i];
            hbT[1][cg + i][r] = ht[i];
            hbT[2][cg + i][r] = hxx[i];
            hbT[3][cg + i][r] = htt[i];
            hbT[4][cg + i][r] = hxt[i];
        }
    }
    __syncthreads();

    // ---- vertical pass: thread = 4 consecutive rows x 1 col, b128 window ----
    const int c  = tid & 31;
    const int r0 = (tid >> 5) << 2;       // 0,4,...,28 (16B-aligned row offset)

    float res[5][4];
    #pragma unroll
    for (int ch = 0; ch < 5; ++ch) {
        float win[28];
        const float4* p = (const float4*)&hbT[ch][c][r0];
        #pragma unroll
        for (int q = 0; q < 7; ++q) {
            float4 v = p[q];
            win[4*q+0] = v.x; win[4*q+1] = v.y; win[4*q+2] = v.z; win[4*q+3] = v.w;
        }
        float a0 = 0.f, a1 = 0.f, a2 = 0.f, a3 = 0.f;
        #pragma unroll
        for (int j = 0; j < KSIZE; ++j) {
            float g = sg[j];
            a0 += g * win[j + 0];
            a1 += g * win[j + 1];
            a2 += g * win[j + 2];
            a3 += g * win[j + 3];
        }
        res[ch][0] = a0; res[ch][1] = a1; res[ch][2] = a2; res[ch][3] = a3;
    }

    float lsum = 0.f;
    #pragma unroll
    for (int rr = 0; rr < 4; ++rr) {
        float vx = res[0][rr], vt = res[1][rr];
        float vxx = res[2][rr], vtt = res[3][rr], vxt = res[4][rr];
        float m1s = vx * vx, m2s = vt * vt, m12 = vx * vt;
        float s1 = vxx - m1s, s2 = vtt - m2s, s12 = vxt - m12;
        float num = (2.f * m12 + C1V) * (2.f * s12 + C2V);
        float den = (m1s + m2s + C1V) * (s1 + s2 + C2V);
        lsum += num / den;
    }

    // ---- block reduction -> per-block partial ----
    #pragma unroll
    for (int off = 32; off > 0; off >>= 1)
        lsum += __shfl_down(lsum, off, 64);
    if ((tid & 63) == 0) swsum[tid >> 6] = lsum;
    __syncthreads();
    if (tid == 0)
        partial[blk] = swsum[0] + swsum[1] + swsum[2] + swsum[3];
}

__global__ __launch_bounds__(256) void ssim_final_kernel(
    const float* __restrict__ partial, float* __restrict__ out)
{
    __shared__ float swsum[4];
    const int tid = threadIdx.x;
    float s = 0.f;
    for (int i = tid; i < NBLK; i += 256) s += partial[i];
    #pragma unroll
    for (int off = 32; off > 0; off >>= 1)
        s += __shfl_down(s, off, 64);
    if ((tid & 63) == 0) swsum[tid >> 6] = s;
    __syncthreads();
    if (tid == 0)
        out[0] = 1.0f - (swsum[0] + swsum[1] + swsum[2] + swsum[3])
                        * (1.0f / ((float)NPLANES * HH * WW));
}

extern "C" void kernel_launch(void* const* d_in, const int* in_sizes, int n_in,
                              void* d_out, int out_size, void* d_ws, size_t ws_size,
                              hipStream_t stream) {
    const float* inp = (const float*)d_in[0];
    const float* tgt = (const float*)d_in[1];
    const float* wgt = (const float*)d_in[2];
    float* out = (float*)d_out;
    float* partial = (float*)d_ws;

    ssim_main_kernel<<<NBLK, 256, 0, stream>>>(inp, tgt, wgt, partial);
    ssim_final_kernel<<<1, 256, 0, stream>>>(partial, out);
}